// Round 1
// baseline (755.413 us; speedup 1.0000x reference)
//
#include <hip/hip_runtime.h>
#include <hip/hip_bf16.h>
#include <stdint.h>

#define T_TOK 4096
#define DM 1024
#define DF 4096
#define NE 8
#define PADROWS 10240   // 8192 + 8*256 (offsets padded to 256-row tiles)

typedef __attribute__((ext_vector_type(8))) short short8;
typedef __attribute__((ext_vector_type(8))) unsigned short ushort8_t;  // 16 B
typedef __attribute__((ext_vector_type(4))) float f32x4;

__device__ __forceinline__ unsigned short f2bf(float f) {
    union { float f; unsigned u; } v; v.f = f;
    unsigned r = v.u + 0x7fffu + ((v.u >> 16) & 1u);   // RNE
    return (unsigned short)(r >> 16);
}

__device__ __forceinline__ void async_cp16(const void* g, void* l) {
    __builtin_amdgcn_global_load_lds(
        (const __attribute__((address_space(1))) unsigned*)g,
        (__attribute__((address_space(3))) unsigned*)l,
        16, 0, 0);
}

// counted waits + raw barrier (memory clobber pins compiler-generated LDS ops)
#define WAITV(n)  asm volatile("s_waitcnt vmcnt(" #n ")" ::: "memory")
#define WAITLGKM() asm volatile("s_waitcnt lgkmcnt(0)" ::: "memory")
#define BAR()     asm volatile("s_barrier" ::: "memory")

// 16B-group swizzle within a 32-elem (64 B) row: 2-way bank aliasing only (free).
// Uses row bits 0..3 — all tile bases are >=128-aligned so local==global bits.
__device__ __forceinline__ int swz(int g, int r) { return g ^ (r & 3) ^ ((r >> 2) & 3); }

// ---------------- router: fp32 logits, top-2, softmax, scatter ----------------
__global__ __launch_bounds__(256) void k_router(
    const float* __restrict__ x, const float* __restrict__ rw,
    const float* __restrict__ rb, int* __restrict__ counts,
    int* __restrict__ listTok, int4* __restrict__ tokRec,
    float2* __restrict__ tokGate)
{
    int l  = threadIdx.x & 63;
    int wv = threadIdx.x >> 6;
    int t  = blockIdx.x * 4 + wv;
    const float* xr = x + (size_t)t * DM;
    float acc[NE];
#pragma unroll
    for (int e = 0; e < NE; ++e) acc[e] = 0.f;
#pragma unroll
    for (int i = 0; i < 16; ++i) {
        int d = i * 64 + l;
        float xv = xr[d];
        const float4* wp = (const float4*)(rw + (size_t)d * NE);
        float4 w0 = wp[0], w1 = wp[1];
        acc[0] += xv * w0.x; acc[1] += xv * w0.y; acc[2] += xv * w0.z; acc[3] += xv * w0.w;
        acc[4] += xv * w1.x; acc[5] += xv * w1.y; acc[6] += xv * w1.z; acc[7] += xv * w1.w;
    }
#pragma unroll
    for (int off = 32; off >= 1; off >>= 1)
#pragma unroll
        for (int e = 0; e < NE; ++e) acc[e] += __shfl_down(acc[e], off);
    if (l == 0) {
        float lg[NE];
#pragma unroll
        for (int e = 0; e < NE; ++e) lg[e] = acc[e] + rb[e];
        int i1 = 0; float s1 = lg[0];
#pragma unroll
        for (int e = 1; e < NE; ++e) if (lg[e] > s1) { s1 = lg[e]; i1 = e; }
        int i2 = -1; float s2 = -3.0e38f;
#pragma unroll
        for (int e = 0; e < NE; ++e) if (e != i1 && lg[e] > s2) { s2 = lg[e]; i2 = e; }
        float g1 = 1.f / (1.f + expf(s2 - s1));
        float g2 = 1.f - g1;
        int p1 = atomicAdd(&counts[i1], 1);
        listTok[i1 * T_TOK + p1] = t;
        int p2 = atomicAdd(&counts[i2], 1);
        listTok[i2 * T_TOK + p2] = t;
        tokRec[t]  = make_int4(i1, p1, i2, p2);
        tokGate[t] = make_float2(g1, g2);
    }
}

// ---------------- 256-padded exclusive scan of counts ----------------
__global__ void k_offsets(const int* __restrict__ counts, int* __restrict__ offsets)
{
    int cum = 0;
    for (int e = 0; e < NE; ++e) { offsets[e] = cum; cum += (counts[e] + 255) & ~255; }
    offsets[NE] = cum;
}

// ---------------- weight pack: fp32 [E][K][N] -> bf16 [E][K/32][N][32] swizzled ----------------
// element (e,k,n): slab=k>>5, g=(k>>3)&3 -> dst[(slab*N+n)*32 + swz(g,n)*8 + (k&7)]
__global__ __launch_bounds__(256) void k_packw(const float* __restrict__ src,
                                               unsigned short* __restrict__ dst,
                                               int K, int N)
{
    __shared__ float tile[64][65];
    int e  = blockIdx.z;
    int n0 = blockIdx.x * 64;
    int k0 = blockIdx.y * 64;
    const float* s    = src + (size_t)e * K * N;
    unsigned short* d = dst + (size_t)e * K * N;
    int tid = threadIdx.x;
#pragma unroll
    for (int i = 0; i < 4; ++i) {
        int u  = i * 256 + tid;
        int kk = u >> 4;
        int nn = (u & 15) * 4;
        float4 v = *(const float4*)(s + (size_t)(k0 + kk) * N + n0 + nn);
        tile[kk][nn] = v.x; tile[kk][nn + 1] = v.y; tile[kk][nn + 2] = v.z; tile[kk][nn + 3] = v.w;
    }
    __syncthreads();
#pragma unroll
    for (int i = 0; i < 2; ++i) {
        int u  = i * 256 + tid;     // 0..511
        int nn = u >> 3;            // 0..63
        int kg = u & 7;             // 0..7
        int gg = kg & 3;
        int n  = n0 + nn;
        ushort8_t o;
#pragma unroll
        for (int j = 0; j < 8; ++j) o[j] = f2bf(tile[kg * 8 + j][nn]);
        size_t slab = (size_t)(k0 >> 5) + (kg >> 2);
        *(ushort8_t*)(d + (slab * N + n) * 32 + (swz(gg, n) << 3)) = o;
    }
}

// ---------------- A pack: gather + fp32->bf16 into [32][PADROWS][32] swizzled ----------------
__global__ __launch_bounds__(256) void k_packa(
    const float* __restrict__ x, const int* __restrict__ listTok,
    const int* __restrict__ counts, const int* __restrict__ offsets,
    unsigned short* __restrict__ ap)
{
    int r0   = blockIdx.x * 64;
    int slab = blockIdx.y;          // 0..31
    int tid  = threadIdx.x;
    __shared__ int toks[64];
    if (tid < 64) {
        int r = r0 + tid;
        int tok = 0;
        int total = offsets[NE];
        if (r < total) {
            int e = 0;
#pragma unroll
            for (int j = 1; j < NE; ++j) if (r >= offsets[j]) e = j;
            int local = r - offsets[e];
            int c = counts[e];
            if (local >= c) local = c - 1;
            if (local < 0) local = 0;
            tok = (c > 0) ? listTok[e * T_TOK + local] : 0;
        }
        toks[tid] = tok;
    }
    __syncthreads();
    int rl = tid >> 2, gg = tid & 3;
    int tok = toks[rl];
    const float4* src = (const float4*)(x + (size_t)tok * DM + slab * 32 + gg * 8);
    float4 v0 = src[0], v1 = src[1];
    ushort8_t o;
    o[0] = f2bf(v0.x); o[1] = f2bf(v0.y); o[2] = f2bf(v0.z); o[3] = f2bf(v0.w);
    o[4] = f2bf(v1.x); o[5] = f2bf(v1.y); o[6] = f2bf(v1.z); o[7] = f2bf(v1.w);
    int rr = r0 + rl;
    *(ushort8_t*)(ap + ((size_t)slab * PADROWS + rr) * 32 + (swz(gg, rr) << 3)) = o;
}

// ---------------- GEMM1: Hp = gelu(A @ W1 + b1). 256x256 tile, BK=32, depth-3 pipeline ----------------
__global__ __launch_bounds__(512, 2) void k_ffn1(
    const unsigned short* __restrict__ ap, const unsigned short* __restrict__ w1p,
    const float* __restrict__ b1, const int* __restrict__ counts,
    const int* __restrict__ offsets, unsigned short* __restrict__ Hp)
{
    __shared__ __align__(16) unsigned short lds[65536];   // 128 KB: 4 slots x (A 8192 + B 8192 elems)
    int i = blockIdx.x;                  // 2048 blocks
    int L = (i & 7) * 256 + (i >> 3);    // XCD-contiguous chunks (bijective, 2048%8==0)
    int mt = L & 15, grp = L >> 4;       // consecutive L share (e,y) -> B-panel L2 reuse
    int y = grp & 15, e = grp >> 4;
    int cnt = counts[e];
    int m0  = mt << 8;
    if (m0 >= cnt) return;
    int R0 = offsets[e] + m0;
    int n0 = y << 8;

    int tid = threadIdx.x, wv = tid >> 6, l = tid & 63;
    int wm = wv >> 2, wn = wv & 3;       // 2x4 waves, wave tile 128x64
    int g = l >> 4, lr = l & 15;

    int offA[8], offB[4];
#pragma unroll
    for (int mi = 0; mi < 8; ++mi) {
        int r = wm * 128 + mi * 16 + lr;
        offA[mi] = r * 32 + (swz(g, r) << 3);
    }
#pragma unroll
    for (int ni = 0; ni < 4; ++ni) {
        int r = wn * 64 + ni * 16 + lr;
        offB[ni] = 8192 + r * 32 + (swz(g, r) << 3);
    }

    const unsigned short* gA = ap + (size_t)R0 * 32;
    const unsigned short* gB = w1p + (size_t)e * DM * DF + (size_t)n0 * 32;

    f32x4 acc[8][4];
#pragma unroll
    for (int a = 0; a < 8; ++a)
#pragma unroll
        for (int b = 0; b < 4; ++b) acc[a][b] = (f32x4)(0.f);

#define STAGE1(t) { \
    unsigned short* sb = lds + (((t) & 3) << 14); \
    const unsigned short* ga = gA + (size_t)(t) * (PADROWS * 32); \
    const unsigned short* gb = gB + (size_t)(t) * (DF * 32); \
    int c0 = wv * 512; \
    async_cp16(ga + c0 + l * 8,        sb + c0); \
    async_cp16(ga + 4096 + c0 + l * 8, sb + 4096 + c0); \
    async_cp16(gb + c0 + l * 8,        sb + 8192 + c0); \
    async_cp16(gb + 4096 + c0 + l * 8, sb + 12288 + c0); }

#define COMPUTE1(t) { \
    const unsigned short* sb = lds + (((t) & 3) << 14); \
    short8 aF[8], bF[4]; \
    _Pragma("unroll") for (int ni = 0; ni < 4; ++ni) bF[ni] = *(const short8*)(sb + offB[ni]); \
    _Pragma("unroll") for (int mi = 0; mi < 8; ++mi) aF[mi] = *(const short8*)(sb + offA[mi]); \
    __builtin_amdgcn_s_setprio(1); \
    _Pragma("unroll") for (int mi = 0; mi < 8; ++mi) \
    _Pragma("unroll") for (int ni = 0; ni < 4; ++ni) \
        acc[mi][ni] = __builtin_amdgcn_mfma_f32_16x16x32_bf16(aF[mi], bF[ni], acc[mi][ni], 0, 0, 0); \
    __builtin_amdgcn_s_setprio(0); }

    // depth-3 prefetch; vmcnt(N): N = 4 loads/tile * tiles-staged-beyond-current.
    // vmcnt retires oldest-first, so the consumed tile is guaranteed landed; the
    // barrier then publishes all waves' DMA writes. Loads stay in flight across barriers.
    STAGE1(0); STAGE1(1); STAGE1(2);
    for (int t = 0; t < 29; ++t) {
        STAGE1(t + 3);
        WAITV(12); BAR();
        COMPUTE1(t);
        BAR();
    }
    WAITV(8); BAR(); COMPUTE1(29); BAR();
    WAITV(4); BAR(); COMPUTE1(30); BAR();
    WAITV(0); BAR(); COMPUTE1(31); BAR();

    // epilogue: bias + exact GELU -> LDS packed image (whole 128 KB) -> vectorized store
#pragma unroll
    for (int ni = 0; ni < 4; ++ni) {
        int nloc = wn * 64 + ni * 16 + lr;          // 0..255
        float bias = b1[e * DF + n0 + nloc];
        int slab = nloc >> 5, c = nloc & 31, g2 = c >> 3;
#pragma unroll
        for (int mi = 0; mi < 8; ++mi) {
#pragma unroll
            for (int rg = 0; rg < 4; ++rg) {
                int m = wm * 128 + mi * 16 + g * 4 + rg;
                float v = acc[mi][ni][rg] + bias;
                v = 0.5f * v * (1.f + erff(v * 0.70710678118f));
                lds[(slab << 13) + m * 32 + (swz(g2, m) << 3) + (c & 7)] = f2bf(v);
            }
        }
    }
    WAITLGKM(); BAR();
#pragma unroll
    for (int j = 0; j < 16; ++j) {
        int u = j * 512 + tid;       // 16-B chunk id, 8192 total
        int elem = u * 8;
        int slab = elem >> 13;
        int rem  = elem & 8191;      // row*32 + col within slab
        *(ushort8_t*)(Hp + ((size_t)((n0 >> 5) + slab) * PADROWS + R0) * 32 + rem) =
            *(const ushort8_t*)(lds + elem);
    }
}

// ---------------- GEMM2: ypart = Hp @ W2 + b2. 256x128 tile, BK=32, depth-3 pipeline ----------------
__global__ __launch_bounds__(512, 2) void k_ffn2(
    const unsigned short* __restrict__ Hp, const unsigned short* __restrict__ w2p,
    const float* __restrict__ b2, const int* __restrict__ counts,
    const int* __restrict__ offsets, float* __restrict__ ypart)
{
    __shared__ __align__(16) unsigned short lds[49152];   // 96 KB: 4 slots x (A 8192 + B 4096 elems)
    int i = blockIdx.x;                  // 1024 blocks
    int L = (i & 7) * 128 + (i >> 3);
    int mt = L & 15, grp = L >> 4;       // grp 0..63
    int y = grp & 7, e = grp >> 3;
    int cnt = counts[e];
    int m0  = mt << 8;
    if (m0 >= cnt) return;
    int R0 = offsets[e] + m0;
    int n0 = y << 7;

    int tid = threadIdx.x, wv = tid >> 6, l = tid & 63;
    int wm = wv >> 1, wn = wv & 1;       // 4x2 waves, wave tile 64x64
    int g = l >> 4, lr = l & 15;

    int offA[4], offB[4];
#pragma unroll
    for (int mi = 0; mi < 4; ++mi) {
        int r = wm * 64 + mi * 16 + lr;
        offA[mi] = r * 32 + (swz(g, r) << 3);
    }
#pragma unroll
    for (int ni = 0; ni < 4; ++ni) {
        int r = wn * 64 + ni * 16 + lr;
        offB[ni] = 8192 + r * 32 + (swz(g, r) << 3);
    }

    const unsigned short* gA = Hp + (size_t)R0 * 32;
    const unsigned short* gB = w2p + (size_t)e * DF * DM + (size_t)n0 * 32;

    f32x4 acc[4][4];
#pragma unroll
    for (int a = 0; a < 4; ++a)
#pragma unroll
        for (int b = 0; b < 4; ++b) acc[a][b] = (f32x4)(0.f);

#define STAGE2(t) { \
    unsigned short* sb = lds + ((t) & 3) * 12288; \
    const unsigned short* ga = gA + (size_t)(t) * (PADROWS * 32); \
    const unsigned short* gb = gB + (size_t)(t) * (DM * 32); \
    int c0 = wv * 512; \
    async_cp16(ga + c0 + l * 8,        sb + c0); \
    async_cp16(ga + 4096 + c0 + l * 8, sb + 4096 + c0); \
    async_cp16(gb + c0 + l * 8,        sb + 8192 + c0); }

#define COMPUTE2(t) { \
    const unsigned short* sb = lds + ((t) & 3) * 12288; \
    short8 aF[4], bF[4]; \
    _Pragma("unroll") for (int ni = 0; ni < 4; ++ni) bF[ni] = *(const short8*)(sb + offB[ni]); \
    _Pragma("unroll") for (int mi = 0; mi < 4; ++mi) aF[mi] = *(const short8*)(sb + offA[mi]); \
    __builtin_amdgcn_s_setprio(1); \
    _Pragma("unroll") for (int mi = 0; mi < 4; ++mi) \
    _Pragma("unroll") for (int ni = 0; ni < 4; ++ni) \
        acc[mi][ni] = __builtin_amdgcn_mfma_f32_16x16x32_bf16(aF[mi], bF[ni], acc[mi][ni], 0, 0, 0); \
    __builtin_amdgcn_s_setprio(0); }

    STAGE2(0); STAGE2(1); STAGE2(2);
    for (int t = 0; t < 125; ++t) {
        STAGE2(t + 3);
        WAITV(9); BAR();
        COMPUTE2(t);
        BAR();
    }
    WAITV(6); BAR(); COMPUTE2(125); BAR();
    WAITV(3); BAR(); COMPUTE2(126); BAR();
    WAITV(0); BAR(); COMPUTE2(127); BAR();

    // epilogue: + b2, plain fp32 store (no atomics); rows >= cnt are dead padding
    float bias[4];
#pragma unroll
    for (int ni = 0; ni < 4; ++ni) bias[ni] = b2[e * DM + n0 + wn * 64 + ni * 16 + lr];
#pragma unroll
    for (int mi = 0; mi < 4; ++mi) {
#pragma unroll
        for (int rg = 0; rg < 4; ++rg) {
            int m = wm * 64 + mi * 16 + g * 4 + rg;
            size_t row = (size_t)R0 + m;
#pragma unroll
            for (int ni = 0; ni < 4; ++ni) {
                ypart[row * DM + n0 + wn * 64 + ni * 16 + lr] = acc[mi][ni][rg] + bias[ni];
            }
        }
    }
}

// ---------------- gather: out[t] = g1*ypart[r1] + g2*ypart[r2] ----------------
__global__ __launch_bounds__(256) void k_gather(
    const float* __restrict__ yp, const int4* __restrict__ rec,
    const float2* __restrict__ gg, const int* __restrict__ offsets,
    float* __restrict__ out)
{
    int t = blockIdx.x;
    int4 rc = rec[t];
    float2 w = gg[t];
    size_t r1 = (size_t)offsets[rc.x] + rc.y;
    size_t r2 = (size_t)offsets[rc.z] + rc.w;
    const float4* a = (const float4*)(yp + r1 * DM);
    const float4* b = (const float4*)(yp + r2 * DM);
    float4 va = a[threadIdx.x], vb = b[threadIdx.x];
    float4 o;
    o.x = w.x * va.x + w.y * vb.x;
    o.y = w.x * va.y + w.y * vb.y;
    o.z = w.x * va.z + w.y * vb.z;
    o.w = w.x * va.w + w.y * vb.w;
    ((float4*)(out + (size_t)t * DM))[threadIdx.x] = o;
}

extern "C" void kernel_launch(void* const* d_in, const int* in_sizes, int n_in,
                              void* d_out, int out_size, void* d_ws, size_t ws_size,
                              hipStream_t stream)
{
    const float* x  = (const float*)d_in[0];
    const float* rw = (const float*)d_in[1];
    const float* rb = (const float*)d_in[2];
    const float* w1 = (const float*)d_in[3];
    const float* b1 = (const float*)d_in[4];
    const float* w2 = (const float*)d_in[5];
    const float* b2 = (const float*)d_in[6];
    float* out = (float*)d_out;

    char* ws = (char*)d_ws;
    // workspace layout — max footprint 214,270,464 B (< round-1-proven 218 MB).
    // w2p ALIASES apack+w1p: written by the second k_packw AFTER k_ffn1 consumed both.
    int*            counts   = (int*)(ws + 0);
    int*            offsets  = (int*)(ws + 128);
    int*            listTok  = (int*)(ws + 512);
    unsigned short* apack    = (unsigned short*)(ws + 262656);     // 21.0 MB [32][10240][32]
    unsigned short* w2p      = (unsigned short*)(ws + 262656);     // 64 MB (alias, after ffn1)
    unsigned short* w1p      = (unsigned short*)(ws + 21234176);   // 64 MB
    unsigned short* Hp       = (unsigned short*)(ws + 88343040);   // 80 MB [128][10240][32]
    float*          ypart    = (float*)(ws + 172229120);           // 40 MB [10240][1024]
    int4*           tokRec   = (int4*)(ws + 214172160);            // 64 KB
    float2*         tokGate  = (float2*)(ws + 214237696);          // 32 KB

    hipMemsetAsync(counts, 0, 32, stream);

    k_router <<<T_TOK / 4, 256, 0, stream>>>(x, rw, rb, counts, listTok, tokRec, tokGate);
    k_offsets<<<1, 1, 0, stream>>>(counts, offsets);
    k_packw  <<<dim3(DF / 64, DM / 64, NE), 256, 0, stream>>>(w1, w1p, DM, DF);
    k_packa  <<<dim3(PADROWS / 64, 32), 256, 0, stream>>>(x, listTok, counts, offsets, apack);
    k_ffn1   <<<2048, 512, 0, stream>>>(apack, w1p, b1, counts, offsets, Hp);
    k_packw  <<<dim3(DM / 64, DF / 64, NE), 256, 0, stream>>>(w2, w2p, DF, DM);
    k_ffn2   <<<1024, 512, 0, stream>>>(Hp, w2p, b2, counts, offsets, ypart);
    k_gather <<<T_TOK, 256, 0, stream>>>(ypart, tokRec, tokGate, offsets, out);
}

// Round 2
// 724.251 us; speedup vs baseline: 1.0430x; 1.0430x over previous
//
#include <hip/hip_runtime.h>
#include <hip/hip_bf16.h>
#include <stdint.h>

#define T_TOK 4096
#define DM 1024
#define DF 4096
#define NE 8
#define PADROWS 10240   // 8192 + 8*256 (offsets padded to 256-row tiles)

typedef __attribute__((ext_vector_type(8))) short short8;
typedef __attribute__((ext_vector_type(8))) unsigned short ushort8_t;  // 16 B
typedef __attribute__((ext_vector_type(4))) float f32x4;

__device__ __forceinline__ unsigned short f2bf(float f) {
    union { float f; unsigned u; } v; v.f = f;
    unsigned r = v.u + 0x7fffu + ((v.u >> 16) & 1u);   // RNE
    return (unsigned short)(r >> 16);
}

__device__ __forceinline__ void async_cp16(const void* g, void* l) {
    __builtin_amdgcn_global_load_lds(
        (const __attribute__((address_space(1))) unsigned*)g,
        (__attribute__((address_space(3))) unsigned*)l,
        16, 0, 0);
}

#define WAITV(n)   asm volatile("s_waitcnt vmcnt(" #n ")" ::: "memory")
#define WAITLGKM() asm volatile("s_waitcnt lgkmcnt(0)" ::: "memory")
#define BAR()      asm volatile("s_barrier" ::: "memory")

// ---------------- router: fp32 logits, top-2, softmax ----------------
__global__ __launch_bounds__(256) void k_router(
    const float* __restrict__ x, const float* __restrict__ rw,
    const float* __restrict__ rb, int* __restrict__ counts,
    int* __restrict__ listTok, int4* __restrict__ tokRec,
    float2* __restrict__ tokGate)
{
    int l  = threadIdx.x & 63;
    int wv = threadIdx.x >> 6;
    int t  = blockIdx.x * 4 + wv;
    const float* xr = x + (size_t)t * DM;
    float acc[NE];
#pragma unroll
    for (int e = 0; e < NE; ++e) acc[e] = 0.f;
#pragma unroll
    for (int i = 0; i < 16; ++i) {
        int d = i * 64 + l;
        float xv = xr[d];
        const float4* wp = (const float4*)(rw + (size_t)d * NE);
        float4 w0 = wp[0], w1 = wp[1];
        acc[0] += xv * w0.x; acc[1] += xv * w0.y; acc[2] += xv * w0.z; acc[3] += xv * w0.w;
        acc[4] += xv * w1.x; acc[5] += xv * w1.y; acc[6] += xv * w1.z; acc[7] += xv * w1.w;
    }
#pragma unroll
    for (int off = 32; off >= 1; off >>= 1)
#pragma unroll
        for (int e = 0; e < NE; ++e) acc[e] += __shfl_down(acc[e], off);
    if (l == 0) {
        float lg[NE];
#pragma unroll
        for (int e = 0; e < NE; ++e) lg[e] = acc[e] + rb[e];
        int i1 = 0; float s1 = lg[0];
#pragma unroll
        for (int e = 1; e < NE; ++e) if (lg[e] > s1) { s1 = lg[e]; i1 = e; }
        int i2 = -1; float s2 = -3.0e38f;
#pragma unroll
        for (int e = 0; e < NE; ++e) if (e != i1 && lg[e] > s2) { s2 = lg[e]; i2 = e; }
        float g1 = 1.f / (1.f + expf(s2 - s1));
        float g2 = 1.f - g1;
        int p1 = atomicAdd(&counts[i1], 1);
        listTok[i1 * T_TOK + p1] = t;
        int p2 = atomicAdd(&counts[i2], 1);
        listTok[i2 * T_TOK + p2] = t;
        tokRec[t]  = make_int4(i1, p1, i2, p2);
        tokGate[t] = make_float2(g1, g2);
    }
}

// ---------------- 256-padded exclusive scan ----------------
__global__ void k_offsets(const int* __restrict__ counts, int* __restrict__ offsets)
{
    int cum = 0;
    for (int e = 0; e < NE; ++e) { offsets[e] = cum; cum += (counts[e] + 255) & ~255; }
    offsets[NE] = cum;
}

// ---------------- weight pack (round-0 proven): fp32 [E][K][N] -> bf16 swizzled [E][K/64][N][64] ----------------
// element (e,k,n) -> dst[e][(k>>6)*N + n]*64 + ((g ^ (n&7))*8 + (k&7)], g=(k&63)>>3
__global__ __launch_bounds__(256) void k_packw(const float* __restrict__ src,
                                               unsigned short* __restrict__ dst,
                                               int K, int N)
{
    __shared__ float tile[64][65];
    int e  = blockIdx.z;
    int n0 = blockIdx.x * 64;
    int k0 = blockIdx.y * 64;
    const float* s    = src + (size_t)e * K * N;
    unsigned short* d = dst + (size_t)e * K * N;
    int tid = threadIdx.x;
#pragma unroll
    for (int i = 0; i < 4; ++i) {
        int u  = i * 256 + tid;
        int kk = u >> 4;
        int nn = (u & 15) * 4;
        float4 v = *(const float4*)(s + (size_t)(k0 + kk) * N + n0 + nn);
        tile[kk][nn] = v.x; tile[kk][nn + 1] = v.y; tile[kk][nn + 2] = v.z; tile[kk][nn + 3] = v.w;
    }
    __syncthreads();
#pragma unroll
    for (int i = 0; i < 4; ++i) {
        int u  = i * 256 + tid;
        int nn = u >> 4;
        int g  = (u >> 1) & 7;
        int h  = (u & 1) * 4;
        int kc = g * 8 + h;
        int n  = n0 + nn;
        ushort4 o;
        o.x = f2bf(tile[kc + 0][nn]); o.y = f2bf(tile[kc + 1][nn]);
        o.z = f2bf(tile[kc + 2][nn]); o.w = f2bf(tile[kc + 3][nn]);
        int gp = g ^ (n & 7);
        size_t off = ((size_t)(k0 >> 6) * N + n) * 64 + gp * 8 + h;
        *(ushort4*)(d + off) = o;
    }
}

// ---------------- A pack (round-0 proven): gather + bf16 into swizzled [16][PADROWS][64] ----------------
__global__ __launch_bounds__(256) void k_packa(
    const float* __restrict__ x, const int* __restrict__ listTok,
    const int* __restrict__ counts, const int* __restrict__ offsets,
    unsigned short* __restrict__ ap)
{
    int r0  = blockIdx.x * 64;
    int kt  = blockIdx.y;
    int tid = threadIdx.x;
    __shared__ int toks[64];
    if (tid < 64) {
        int r = r0 + tid;
        int tok = 0;
        int total = offsets[NE];
        if (r < total) {
            int e = 0;
#pragma unroll
            for (int j = 1; j < NE; ++j) if (r >= offsets[j]) e = j;
            int local = r - offsets[e];
            int c = counts[e];
            if (local >= c) local = c - 1;
            if (local < 0) local = 0;
            tok = (c > 0) ? listTok[e * T_TOK + local] : 0;
        }
        toks[tid] = tok;
    }
    __syncthreads();
#pragma unroll
    for (int i = 0; i < 4; ++i) {
        int u  = i * 256 + tid;
        int rl = u >> 4;
        int g  = (u >> 1) & 7;
        int h  = (u & 1) * 4;
        int tok = toks[rl];
        float4 v = *(const float4*)(x + (size_t)tok * DM + kt * 64 + g * 8 + h);
        ushort4 o; o.x = f2bf(v.x); o.y = f2bf(v.y); o.z = f2bf(v.z); o.w = f2bf(v.w);
        int row = r0 + rl;
        int gp  = g ^ (row & 7);
        size_t off = ((size_t)kt * PADROWS + row) * 64 + gp * 8 + h;
        *(ushort4*)(ap + off) = o;
    }
}

// ==================== GEMM1: 256x256 tile, BK=64, 4-phase pipelined ====================
// waves 2Mx4N (wave tile 128x64, 8 m-frags x 4 n-frags). 2 LDS slots of (A 32K + B 32K).
// Schedule per tile T (slot T&1), quadrants snake (mh0,nh0)(mh0,nh1)(mh1,nh1)(mh1,nh0):
//   ph1: read A-mh0(8)+B-nh0(4, HELD), stage T+1.A1 (other slot)
//   ph2: read B-nh1(4),               stage T+1.B1 (other slot)
//   ph3: read A-mh1(8),               stage T+2.B0 (cur slot; B last read ph2, a barrier ago)
//   ph4: (no reads)                   stage T+2.A0 (cur slot; A last read ph3) + vmcnt(4)
// vmcnt(4) retires all of T+1 (8 loads/tile), leaves T+2's 4 in flight — never drains to 0.
__global__ __launch_bounds__(512, 2) void k_ffn1(
    const unsigned short* __restrict__ ap, const unsigned short* __restrict__ w1p,
    const float* __restrict__ b1, const int* __restrict__ counts,
    const int* __restrict__ offsets, unsigned short* __restrict__ Hp)
{
    __shared__ __align__(16) unsigned short lds[65536];   // 128 KB
    const int NT = 16;                   // K = 1024 / 64
    int i = blockIdx.x;                  // 2048 blocks
    int L = (i & 7) * 256 + (i >> 3);    // XCD-contiguous chunks
    int mt = L & 15, grp = L >> 4;       // consecutive L share (e,y) B-panel
    int y = grp & 15, e = grp >> 4;
    int cnt = counts[e];
    int m0  = mt << 8;
    if (m0 >= cnt) return;
    int R0 = offsets[e] + m0;
    int n0 = y << 8;

    int tid = threadIdx.x, wv = tid >> 6, l = tid & 63;
    int wm = wv >> 2, wn = wv & 3;
    int g4 = l >> 4, lr = l & 15;
    int gp0 = g4 ^ (lr & 7);
    int dK  = ((gp0 ^ 4) - gp0) * 8;     // ks=1 group delta (ushorts)
    int baseA = (wm * 128 + lr) * 64 + gp0 * 8;
    int baseB = 16384 + (wn * 64 + lr) * 64 + gp0 * 8;

    const unsigned short* gA = ap + (size_t)R0 * 64;
    const unsigned short* gB = w1p + (size_t)e * DM * DF + (size_t)n0 * 64;

    f32x4 acc[8][4];
#pragma unroll
    for (int a = 0; a < 8; ++a)
#pragma unroll
        for (int b = 0; b < 4; ++b) acc[a][b] = (f32x4)(0.f);

#define ST_A1(T, h) { int ch = wv * 2; \
    const unsigned short* gp_ = gA + (size_t)(T) * (PADROWS * 64) + (h) * 8192; \
    unsigned short* dp_ = lds + ((T) & 1) * 32768 + (h) * 8192; \
    async_cp16(gp_ + ch * 512 + l * 8, dp_ + ch * 512); \
    async_cp16(gp_ + (ch + 1) * 512 + l * 8, dp_ + (ch + 1) * 512); }

#define ST_B1(T, h) { int ch = wv * 2; \
    const unsigned short* gp_ = gB + (size_t)(T) * (DF * 64) + (h) * 8192; \
    unsigned short* dp_ = lds + ((T) & 1) * 32768 + 16384 + (h) * 8192; \
    async_cp16(gp_ + ch * 512 + l * 8, dp_ + ch * 512); \
    async_cp16(gp_ + (ch + 1) * 512 + l * 8, dp_ + (ch + 1) * 512); }

#define RD_A1(MH) { _Pragma("unroll") for (int mi = 0; mi < 4; ++mi) { \
    aF[mi][0] = *(const short8*)(sb + baseA + ((MH) * 4 + mi) * 1024); \
    aF[mi][1] = *(const short8*)(sb + baseA + ((MH) * 4 + mi) * 1024 + dK); } }

#define RD_B1(DST, NH) { _Pragma("unroll") for (int ni = 0; ni < 2; ++ni) { \
    DST[ni][0] = *(const short8*)(sb + baseB + ((NH) * 2 + ni) * 1024); \
    DST[ni][1] = *(const short8*)(sb + baseB + ((NH) * 2 + ni) * 1024 + dK); } }

#define MM16(MH, BF, NB) \
    _Pragma("unroll") for (int ks = 0; ks < 2; ++ks) \
    _Pragma("unroll") for (int mi = 0; mi < 4; ++mi) \
    _Pragma("unroll") for (int ni = 0; ni < 2; ++ni) \
        acc[(MH) * 4 + mi][(NB) + ni] = __builtin_amdgcn_mfma_f32_16x16x32_bf16( \
            aF[mi][ks], BF[ni][ks], acc[(MH) * 4 + mi][(NB) + ni], 0, 0, 0);

    // prologue: tile0 full + T1.B0 + T1.A0; retire tile0 (leave 4 in flight)
    ST_A1(0, 0); ST_A1(0, 1); ST_B1(0, 0); ST_B1(0, 1);
    ST_B1(1, 0); ST_A1(1, 0);
    WAITV(4); BAR();

    for (int T = 0; T < NT; ++T) {
        unsigned short* sb = lds + (T & 1) * 32768;
        short8 aF[4][2], bH0[2][2], bF1[2][2];
        // ph1 (mh0,nh0)
        RD_A1(0); RD_B1(bH0, 0);
        if (T + 1 < NT) ST_A1(T + 1, 1);
        BAR(); WAITLGKM();
        __builtin_amdgcn_s_setprio(1); MM16(0, bH0, 0); __builtin_amdgcn_s_setprio(0);
        BAR();
        // ph2 (mh0,nh1)
        RD_B1(bF1, 1);
        if (T + 1 < NT) ST_B1(T + 1, 1);
        BAR(); WAITLGKM();
        __builtin_amdgcn_s_setprio(1); MM16(0, bF1, 2); __builtin_amdgcn_s_setprio(0);
        BAR();
        // ph3 (mh1,nh1)
        RD_A1(1);
        if (T + 2 < NT) ST_B1(T + 2, 0);
        BAR(); WAITLGKM();
        __builtin_amdgcn_s_setprio(1); MM16(1, bF1, 2); __builtin_amdgcn_s_setprio(0);
        BAR();
        // ph4 (mh1,nh0)
        if (T + 2 < NT) ST_A1(T + 2, 0);
        if (T == NT - 2) { WAITV(0); } else if (T < NT - 2) { WAITV(4); }
        BAR();
        __builtin_amdgcn_s_setprio(1); MM16(1, bH0, 0); __builtin_amdgcn_s_setprio(0);
        BAR();
    }
#undef ST_A1
#undef ST_B1
#undef RD_A1
#undef RD_B1
#undef MM16

    // epilogue: bias + exact GELU -> full 128 KB LDS image (Hp layout) -> vector store
#pragma unroll
    for (int ni = 0; ni < 4; ++ni) {
        int nloc = wn * 64 + ni * 16 + lr;
        float bias = b1[e * DF + n0 + nloc];
        int slab = nloc >> 6, kc = nloc & 63, gg = kc >> 3, kr = kc & 7;
#pragma unroll
        for (int mi = 0; mi < 8; ++mi) {
#pragma unroll
            for (int rg = 0; rg < 4; ++rg) {
                int m = wm * 128 + mi * 16 + g4 * 4 + rg;
                float v = acc[mi][ni][rg] + bias;
                v = 0.5f * v * (1.f + erff(v * 0.70710678118f));
                lds[slab * 16384 + m * 64 + ((gg ^ (m & 7)) << 3) + kr] = f2bf(v);
            }
        }
    }
    WAITLGKM(); BAR();
#pragma unroll
    for (int j = 0; j < 16; ++j) {
        int u = j * 512 + tid;
        int elem = u * 8;
        int slab = elem >> 14;
        int rem  = elem & 16383;
        *(ushort8_t*)(Hp + ((size_t)((n0 >> 6) + slab) * PADROWS + R0) * 64 + rem) =
            *(const ushort8_t*)(lds + elem);
    }
}

// ==================== GEMM2: 256x128 tile, BK=64, K=4096 (64 tiles), 4-phase pipelined ====================
// waves 4Mx2N (wave tile 64x64, 4 m-frags x 4 n-frags). 2 LDS slots of (A 32K + B 16K) = 96 KB.
__global__ __launch_bounds__(512, 2) void k_ffn2(
    const unsigned short* __restrict__ Hp, const unsigned short* __restrict__ w2p,
    const float* __restrict__ b2, const int* __restrict__ counts,
    const int* __restrict__ offsets, float* __restrict__ ypart)
{
    __shared__ __align__(16) unsigned short lds[49152];   // 96 KB
    const int NT = 64;                   // K = 4096 / 64
    int i = blockIdx.x;                  // 1024 blocks
    int L = (i & 7) * 128 + (i >> 3);
    int mt = L & 15, grp = L >> 4;       // grp 0..63
    int y = grp & 7, e = grp >> 3;
    int cnt = counts[e];
    int m0  = mt << 8;
    if (m0 >= cnt) return;
    int R0 = offsets[e] + m0;
    int n0 = y << 7;

    int tid = threadIdx.x, wv = tid >> 6, l = tid & 63;
    int wm = wv >> 1, wn = wv & 1;
    int g4 = l >> 4, lr = l & 15;
    int gp0 = g4 ^ (lr & 7);
    int dK  = ((gp0 ^ 4) - gp0) * 8;
    int baseA = (wm * 64 + lr) * 64 + gp0 * 8;
    int baseB = 16384 + (wn * 64 + lr) * 64 + gp0 * 8;

    const unsigned short* gA = Hp + (size_t)R0 * 64;
    const unsigned short* gB = w2p + (size_t)e * DF * DM + (size_t)n0 * 64;

    f32x4 acc[4][4];
#pragma unroll
    for (int a = 0; a < 4; ++a)
#pragma unroll
        for (int b = 0; b < 4; ++b) acc[a][b] = (f32x4)(0.f);

#define ST_A2(T, h) { int ch = wv * 2; \
    const unsigned short* gp_ = gA + (size_t)(T) * (PADROWS * 64) + (h) * 8192; \
    unsigned short* dp_ = lds + ((T) & 1) * 24576 + (h) * 8192; \
    async_cp16(gp_ + ch * 512 + l * 8, dp_ + ch * 512); \
    async_cp16(gp_ + (ch + 1) * 512 + l * 8, dp_ + (ch + 1) * 512); }

#define ST_B2(T, h) { \
    const unsigned short* gp_ = gB + (size_t)(T) * (DM * 64) + (h) * 4096; \
    unsigned short* dp_ = lds + ((T) & 1) * 24576 + 16384 + (h) * 4096; \
    async_cp16(gp_ + wv * 512 + l * 8, dp_ + wv * 512); }

#define RD_A2(MH) { _Pragma("unroll") for (int mi = 0; mi < 2; ++mi) { \
    aF[mi][0] = *(const short8*)(sb + baseA + ((MH) * 2 + mi) * 1024); \
    aF[mi][1] = *(const short8*)(sb + baseA + ((MH) * 2 + mi) * 1024 + dK); } }

#define RD_B2(DST, NH) { _Pragma("unroll") for (int ni = 0; ni < 2; ++ni) { \
    DST[ni][0] = *(const short8*)(sb + baseB + ((NH) * 2 + ni) * 1024); \
    DST[ni][1] = *(const short8*)(sb + baseB + ((NH) * 2 + ni) * 1024 + dK); } }

#define MM8(MH, BF, NB) \
    _Pragma("unroll") for (int ks = 0; ks < 2; ++ks) \
    _Pragma("unroll") for (int mi = 0; mi < 2; ++mi) \
    _Pragma("unroll") for (int ni = 0; ni < 2; ++ni) \
        acc[(MH) * 2 + mi][(NB) + ni] = __builtin_amdgcn_mfma_f32_16x16x32_bf16( \
            aF[mi][ks], BF[ni][ks], acc[(MH) * 2 + mi][(NB) + ni], 0, 0, 0);

    ST_A2(0, 0); ST_A2(0, 1); ST_B2(0, 0); ST_B2(0, 1);
    ST_B2(1, 0); ST_A2(1, 0);
    WAITV(3); BAR();

    for (int T = 0; T < NT; ++T) {
        unsigned short* sb = lds + (T & 1) * 24576;
        short8 aF[2][2], bH0[2][2], bF1[2][2];
        // ph1 (mh0,nh0)
        RD_A2(0); RD_B2(bH0, 0);
        if (T + 1 < NT) ST_A2(T + 1, 1);
        BAR(); WAITLGKM();
        __builtin_amdgcn_s_setprio(1); MM8(0, bH0, 0); __builtin_amdgcn_s_setprio(0);
        BAR();
        // ph2 (mh0,nh1)
        RD_B2(bF1, 1);
        if (T + 1 < NT) ST_B2(T + 1, 1);
        BAR(); WAITLGKM();
        __builtin_amdgcn_s_setprio(1); MM8(0, bF1, 2); __builtin_amdgcn_s_setprio(0);
        BAR();
        // ph3 (mh1,nh1)
        RD_A2(1);
        if (T + 2 < NT) ST_B2(T + 2, 0);
        BAR(); WAITLGKM();
        __builtin_amdgcn_s_setprio(1); MM8(1, bF1, 2); __builtin_amdgcn_s_setprio(0);
        BAR();
        // ph4 (mh1,nh0)
        if (T + 2 < NT) ST_A2(T + 2, 0);
        if (T == NT - 2) { WAITV(0); } else if (T < NT - 2) { WAITV(3); }
        BAR();
        __builtin_amdgcn_s_setprio(1); MM8(1, bH0, 0); __builtin_amdgcn_s_setprio(0);
        BAR();
    }
#undef ST_A2
#undef ST_B2
#undef RD_A2
#undef RD_B2
#undef MM8

    // epilogue: + b2, plain fp32 store; padded rows are dead
    float bias[4];
#pragma unroll
    for (int ni = 0; ni < 4; ++ni) bias[ni] = b2[e * DM + n0 + wn * 64 + ni * 16 + lr];
#pragma unroll
    for (int mi = 0; mi < 4; ++mi) {
#pragma unroll
        for (int rg = 0; rg < 4; ++rg) {
            int m = wm * 64 + mi * 16 + g4 * 4 + rg;
            float* orow = ypart + ((size_t)R0 + m) * DM;
#pragma unroll
            for (int ni = 0; ni < 4; ++ni)
                orow[n0 + wn * 64 + ni * 16 + lr] = acc[mi][ni][rg] + bias[ni];
        }
    }
}

// ---------------- gather: out[t] = g1*ypart[r1] + g2*ypart[r2] ----------------
__global__ __launch_bounds__(256) void k_gather(
    const float* __restrict__ yp, const int4* __restrict__ rec,
    const float2* __restrict__ gg, const int* __restrict__ offsets,
    float* __restrict__ out)
{
    int t = blockIdx.x;
    int4 rc = rec[t];
    float2 w = gg[t];
    size_t r1 = (size_t)offsets[rc.x] + rc.y;
    size_t r2 = (size_t)offsets[rc.z] + rc.w;
    const float4* a = (const float4*)(yp + r1 * DM);
    const float4* b = (const float4*)(yp + r2 * DM);
    float4 va = a[threadIdx.x], vb = b[threadIdx.x];
    float4 o;
    o.x = w.x * va.x + w.y * vb.x;
    o.y = w.x * va.y + w.y * vb.y;
    o.z = w.x * va.z + w.y * vb.z;
    o.w = w.x * va.w + w.y * vb.w;
    ((float4*)(out + (size_t)t * DM))[threadIdx.x] = o;
}

extern "C" void kernel_launch(void* const* d_in, const int* in_sizes, int n_in,
                              void* d_out, int out_size, void* d_ws, size_t ws_size,
                              hipStream_t stream)
{
    const float* x  = (const float*)d_in[0];
    const float* rw = (const float*)d_in[1];
    const float* rb = (const float*)d_in[2];
    const float* w1 = (const float*)d_in[3];
    const float* b1 = (const float*)d_in[4];
    const float* w2 = (const float*)d_in[5];
    const float* b2 = (const float*)d_in[6];
    float* out = (float*)d_out;

    char* ws = (char*)d_ws;
    // workspace layout — footprint 214,270,464 B (same as round-1, proven).
    // w2p ALIASES apack+w1p region: written by 2nd k_packw AFTER k_ffn1 consumed both.
    int*            counts   = (int*)(ws + 0);
    int*            offsets  = (int*)(ws + 128);
    int*            listTok  = (int*)(ws + 512);
    unsigned short* apack    = (unsigned short*)(ws + 262656);     // 21.0 MB [16][10240][64]
    unsigned short* w2p      = (unsigned short*)(ws + 262656);     // 64 MB (alias, after ffn1)
    unsigned short* w1p      = (unsigned short*)(ws + 21234176);   // 64 MB
    unsigned short* Hp       = (unsigned short*)(ws + 88343040);   // 83.9 MB [64][10240][64]
    float*          ypart    = (float*)(ws + 172229120);           // 41.9 MB [10240][1024]
    int4*           tokRec   = (int4*)(ws + 214172160);            // 64 KB
    float2*         tokGate  = (float2*)(ws + 214237696);          // 32 KB

    hipMemsetAsync(counts, 0, 32, stream);

    k_router <<<T_TOK / 4, 256, 0, stream>>>(x, rw, rb, counts, listTok, tokRec, tokGate);
    k_offsets<<<1, 1, 0, stream>>>(counts, offsets);
    k_packw  <<<dim3(DF / 64, DM / 64, NE), 256, 0, stream>>>(w1, w1p, DM, DF);
    k_packa  <<<dim3(PADROWS / 64, 16), 256, 0, stream>>>(x, listTok, counts, offsets, apack);
    k_ffn1   <<<2048, 512, 0, stream>>>(apack, w1p, b1, counts, offsets, Hp);
    k_packw  <<<dim3(DM / 64, DF / 64, NE), 256, 0, stream>>>(w2, w2p, DF, DM);
    k_ffn2   <<<1024, 512, 0, stream>>>(Hp, w2p, b2, counts, offsets, ypart);
    k_gather <<<T_TOK, 256, 0, stream>>>(ypart, tokRec, tokGate, offsets, out);
}

// Round 3
// 652.734 us; speedup vs baseline: 1.1573x; 1.1096x over previous
//
#include <hip/hip_runtime.h>
#include <hip/hip_bf16.h>
#include <stdint.h>

#define T_TOK 4096
#define DM 1024
#define DF 4096
#define NE 8
#define PADROWS 10240   // 8192 + 8*256 (offsets padded to 256-row granularity)

typedef __attribute__((ext_vector_type(8))) short short8;
typedef __attribute__((ext_vector_type(8))) unsigned short ushort8_t;  // 16 B
typedef __attribute__((ext_vector_type(4))) float f32x4;

__device__ __forceinline__ unsigned short f2bf(float f) {
    union { float f; unsigned u; } v; v.f = f;
    unsigned r = v.u + 0x7fffu + ((v.u >> 16) & 1u);   // RNE
    return (unsigned short)(r >> 16);
}

__device__ __forceinline__ void async_cp16(const void* g, void* l) {
    __builtin_amdgcn_global_load_lds(
        (const __attribute__((address_space(1))) unsigned*)g,
        (__attribute__((address_space(3))) unsigned*)l,
        16, 0, 0);
}

// ---------------- router: fp32 logits, top-2, softmax ----------------
__global__ __launch_bounds__(256) void k_router(
    const float* __restrict__ x, const float* __restrict__ rw,
    const float* __restrict__ rb, int* __restrict__ counts,
    int* __restrict__ listTok, int4* __restrict__ tokRec,
    float2* __restrict__ tokGate)
{
    int l  = threadIdx.x & 63;
    int wv = threadIdx.x >> 6;
    int t  = blockIdx.x * 4 + wv;
    const float* xr = x + (size_t)t * DM;
    float acc[NE];
#pragma unroll
    for (int e = 0; e < NE; ++e) acc[e] = 0.f;
#pragma unroll
    for (int i = 0; i < 16; ++i) {
        int d = i * 64 + l;
        float xv = xr[d];
        const float4* wp = (const float4*)(rw + (size_t)d * NE);
        float4 w0 = wp[0], w1 = wp[1];
        acc[0] += xv * w0.x; acc[1] += xv * w0.y; acc[2] += xv * w0.z; acc[3] += xv * w0.w;
        acc[4] += xv * w1.x; acc[5] += xv * w1.y; acc[6] += xv * w1.z; acc[7] += xv * w1.w;
    }
#pragma unroll
    for (int off = 32; off >= 1; off >>= 1)
#pragma unroll
        for (int e = 0; e < NE; ++e) acc[e] += __shfl_down(acc[e], off);
    if (l == 0) {
        float lg[NE];
#pragma unroll
        for (int e = 0; e < NE; ++e) lg[e] = acc[e] + rb[e];
        int i1 = 0; float s1 = lg[0];
#pragma unroll
        for (int e = 1; e < NE; ++e) if (lg[e] > s1) { s1 = lg[e]; i1 = e; }
        int i2 = -1; float s2 = -3.0e38f;
#pragma unroll
        for (int e = 0; e < NE; ++e) if (e != i1 && lg[e] > s2) { s2 = lg[e]; i2 = e; }
        float g1 = 1.f / (1.f + expf(s2 - s1));
        float g2 = 1.f - g1;
        int p1 = atomicAdd(&counts[i1], 1);
        listTok[i1 * T_TOK + p1] = t;
        int p2 = atomicAdd(&counts[i2], 1);
        listTok[i2 * T_TOK + p2] = t;
        tokRec[t]  = make_int4(i1, p1, i2, p2);
        tokGate[t] = make_float2(g1, g2);
    }
}

// ---------------- 256-padded exclusive scan ----------------
__global__ void k_offsets(const int* __restrict__ counts, int* __restrict__ offsets)
{
    int cum = 0;
    for (int e = 0; e < NE; ++e) { offsets[e] = cum; cum += (counts[e] + 255) & ~255; }
    offsets[NE] = cum;
}

// ---------------- weight pack: fp32 [E][K][N] -> bf16 swizzled [E][K/64][N][64] ----------------
// element (e,k,n) -> dst[e][(k>>6)*N + n]*64 + ((g ^ (n&7))*8 + (k&7)], g=(k&63)>>3
__global__ __launch_bounds__(256) void k_packw(const float* __restrict__ src,
                                               unsigned short* __restrict__ dst,
                                               int K, int N)
{
    __shared__ float tile[64][65];
    int e  = blockIdx.z;
    int n0 = blockIdx.x * 64;
    int k0 = blockIdx.y * 64;
    const float* s    = src + (size_t)e * K * N;
    unsigned short* d = dst + (size_t)e * K * N;
    int tid = threadIdx.x;
#pragma unroll
    for (int i = 0; i < 4; ++i) {
        int u  = i * 256 + tid;
        int kk = u >> 4;
        int nn = (u & 15) * 4;
        float4 v = *(const float4*)(s + (size_t)(k0 + kk) * N + n0 + nn);
        tile[kk][nn] = v.x; tile[kk][nn + 1] = v.y; tile[kk][nn + 2] = v.z; tile[kk][nn + 3] = v.w;
    }
    __syncthreads();
#pragma unroll
    for (int i = 0; i < 4; ++i) {
        int u  = i * 256 + tid;
        int nn = u >> 4;
        int g  = (u >> 1) & 7;
        int h  = (u & 1) * 4;
        int kc = g * 8 + h;
        int n  = n0 + nn;
        ushort4 o;
        o.x = f2bf(tile[kc + 0][nn]); o.y = f2bf(tile[kc + 1][nn]);
        o.z = f2bf(tile[kc + 2][nn]); o.w = f2bf(tile[kc + 3][nn]);
        int gp = g ^ (n & 7);
        size_t off = ((size_t)(k0 >> 6) * N + n) * 64 + gp * 8 + h;
        *(ushort4*)(d + off) = o;
    }
}

// ---------------- A pack: gather + bf16 into swizzled [16][PADROWS][64] ----------------
__global__ __launch_bounds__(256) void k_packa(
    const float* __restrict__ x, const int* __restrict__ listTok,
    const int* __restrict__ counts, const int* __restrict__ offsets,
    unsigned short* __restrict__ ap)
{
    int r0  = blockIdx.x * 64;
    int kt  = blockIdx.y;
    int tid = threadIdx.x;
    __shared__ int toks[64];
    if (tid < 64) {
        int r = r0 + tid;
        int tok = 0;
        int total = offsets[NE];
        if (r < total) {
            int e = 0;
#pragma unroll
            for (int j = 1; j < NE; ++j) if (r >= offsets[j]) e = j;
            int local = r - offsets[e];
            int c = counts[e];
            if (local >= c) local = c - 1;
            if (local < 0) local = 0;
            tok = (c > 0) ? listTok[e * T_TOK + local] : 0;
        }
        toks[tid] = tok;
    }
    __syncthreads();
#pragma unroll
    for (int i = 0; i < 4; ++i) {
        int u  = i * 256 + tid;
        int rl = u >> 4;
        int g  = (u >> 1) & 7;
        int h  = (u & 1) * 4;
        int tok = toks[rl];
        float4 v = *(const float4*)(x + (size_t)tok * DM + kt * 64 + g * 8 + h);
        ushort4 o; o.x = f2bf(v.x); o.y = f2bf(v.y); o.z = f2bf(v.z); o.w = f2bf(v.w);
        int row = r0 + rl;
        int gp  = g ^ (row & 7);
        size_t off = ((size_t)kt * PADROWS + row) * 64 + gp * 8 + h;
        *(ushort4*)(ap + off) = o;
    }
}

// ==================== GEMM1: 128x128 tile, BK=64, m97-structure (compiler-scheduled waits) ====================
// grid 8192 = 8 XCD x 32 mt x 32 y. e == XCD (i&7): counts near-uniform so balance ok;
// mt fastest within an XCD so concurrent blocks share the (e,y) B-panel (256 KB, L2-resident)
// and the expert's A-slice (~2.6 MB) stays L2-resident across y rounds.
__global__ __launch_bounds__(256) void k_ffn1(
    const unsigned short* __restrict__ ap, const unsigned short* __restrict__ w1p,
    const float* __restrict__ b1, const int* __restrict__ counts,
    const int* __restrict__ offsets, unsigned short* __restrict__ Hp)
{
    __shared__ __align__(16) unsigned short lsA[128 * 64];   // 16 KB
    __shared__ __align__(16) unsigned short lsB[128 * 64];   // 16 KB
    int i  = blockIdx.x;
    int e  = i & 7;
    int j  = i >> 3;
    int mt = j & 31;
    int y  = j >> 5;          // 0..31
    int cnt = counts[e];
    int m0  = mt << 7;
    if (m0 >= cnt) return;
    int hbase = offsets[e];
    int n0    = y << 7;
    int tid = threadIdx.x, wv = tid >> 6, l = tid & 63;
    int wm = wv & 1, wn = wv >> 1;

    const unsigned short* srcA = ap + ((size_t)hbase + m0) * 64;
    const unsigned short* srcB = w1p + (size_t)e * DM * DF;

    f32x4 acc[4][4];
#pragma unroll
    for (int a = 0; a < 4; ++a)
#pragma unroll
        for (int b = 0; b < 4; ++b) acc[a][b] = (f32x4)(0.f);

    for (int kt = 0; kt < 16; ++kt) {
        const unsigned short* gA = srcA + (size_t)kt * PADROWS * 64;
        const unsigned short* gB = srcB + ((size_t)kt * DF + n0) * 64;
#pragma unroll
        for (int jj = 0; jj < 4; ++jj) {
            int c = (wv * 4 + jj) * 512;   // 1 KB chunks (elements)
            async_cp16(gA + c + l * 8, lsA + c);
            async_cp16(gB + c + l * 8, lsB + c);
        }
        __syncthreads();
#pragma unroll
        for (int ks = 0; ks < 2; ++ks) {
            short8 aF[4], bF[4];
#pragma unroll
            for (int mi = 0; mi < 4; ++mi) {
                int row = wm * 64 + mi * 16 + (l & 15);
                int g   = ks * 4 + (l >> 4);
                aF[mi] = *(const short8*)&lsA[row * 64 + ((g ^ (row & 7)) << 3)];
            }
#pragma unroll
            for (int ni = 0; ni < 4; ++ni) {
                int row = wn * 64 + ni * 16 + (l & 15);
                int g   = ks * 4 + (l >> 4);
                bF[ni] = *(const short8*)&lsB[row * 64 + ((g ^ (row & 7)) << 3)];
            }
#pragma unroll
            for (int mi = 0; mi < 4; ++mi)
#pragma unroll
                for (int ni = 0; ni < 4; ++ni)
                    acc[mi][ni] = __builtin_amdgcn_mfma_f32_16x16x32_bf16(aF[mi], bF[ni], acc[mi][ni], 0, 0, 0);
        }
        __syncthreads();
    }

    // epilogue: bias + exact GELU -> LDS packed image -> vectorized store
    int q = l >> 4, cn = l & 15;
#pragma unroll
    for (int mi = 0; mi < 4; ++mi) {
#pragma unroll
        for (int ni = 0; ni < 4; ++ni) {
            int nloc = wn * 64 + ni * 16 + cn;             // 0..127
            float bias = b1[e * DF + n0 + nloc];
            unsigned short* base = (nloc & 64) ? lsB : lsA;
            int kc = nloc & 63, g = kc >> 3;
#pragma unroll
            for (int rg = 0; rg < 4; ++rg) {
                int m = wm * 64 + mi * 16 + q * 4 + rg;
                float v = acc[mi][ni][rg] + bias;
                v = 0.5f * v * (1.f + erff(v * 0.70710678118f));
                int gp = g ^ (m & 7);
                base[m * 64 + gp * 8 + (kc & 7)] = f2bf(v);
            }
        }
    }
    __syncthreads();
    {
        int c = tid >> 7;            // slab 0/1
        int r = tid & 127;           // row
        const unsigned short* s = (c ? lsB : lsA) + r * 64;
        unsigned short* dst = Hp + (((size_t)(n0 >> 6) + c) * PADROWS + hbase + m0 + r) * 64;
#pragma unroll
        for (int jj = 0; jj < 8; ++jj)
            *(ushort8_t*)(dst + jj * 8) = *(const ushort8_t*)(s + jj * 8);
    }
}

// ==================== GEMM2: 128x128 tile, BK=64, K=4096, m97-structure, plain store ====================
// grid 2048 = 8 XCD x 32 mt x 8 y; e == XCD; mt fastest (shared 1 MB B-panel per y).
__global__ __launch_bounds__(256) void k_ffn2(
    const unsigned short* __restrict__ Hp, const unsigned short* __restrict__ w2p,
    const float* __restrict__ b2, const int* __restrict__ counts,
    const int* __restrict__ offsets, float* __restrict__ ypart)
{
    __shared__ __align__(16) unsigned short lsA[128 * 64];
    __shared__ __align__(16) unsigned short lsB[128 * 64];
    int i  = blockIdx.x;
    int e  = i & 7;
    int j  = i >> 3;
    int mt = j & 31;
    int y  = j >> 5;          // 0..7
    int cnt = counts[e];
    int m0  = mt << 7;
    if (m0 >= cnt) return;
    int R0 = offsets[e] + m0;
    int n0 = y << 7;
    int tid = threadIdx.x, wv = tid >> 6, l = tid & 63;
    int wm = wv & 1, wn = wv >> 1;

    const unsigned short* srcA = Hp + (size_t)R0 * 64;
    const unsigned short* srcB = w2p + (size_t)e * DF * DM;

    f32x4 acc[4][4];
#pragma unroll
    for (int a = 0; a < 4; ++a)
#pragma unroll
        for (int b = 0; b < 4; ++b) acc[a][b] = (f32x4)(0.f);

    for (int kt = 0; kt < 64; ++kt) {
        const unsigned short* gA = srcA + (size_t)kt * PADROWS * 64;
        const unsigned short* gB = srcB + ((size_t)kt * DM + n0) * 64;
#pragma unroll
        for (int jj = 0; jj < 4; ++jj) {
            int c = (wv * 4 + jj) * 512;
            async_cp16(gA + c + l * 8, lsA + c);
            async_cp16(gB + c + l * 8, lsB + c);
        }
        __syncthreads();
#pragma unroll
        for (int ks = 0; ks < 2; ++ks) {
            short8 aF[4], bF[4];
#pragma unroll
            for (int mi = 0; mi < 4; ++mi) {
                int row = wm * 64 + mi * 16 + (l & 15);
                int g   = ks * 4 + (l >> 4);
                aF[mi] = *(const short8*)&lsA[row * 64 + ((g ^ (row & 7)) << 3)];
            }
#pragma unroll
            for (int ni = 0; ni < 4; ++ni) {
                int row = wn * 64 + ni * 16 + (l & 15);
                int g   = ks * 4 + (l >> 4);
                bF[ni] = *(const short8*)&lsB[row * 64 + ((g ^ (row & 7)) << 3)];
            }
#pragma unroll
            for (int mi = 0; mi < 4; ++mi)
#pragma unroll
                for (int ni = 0; ni < 4; ++ni)
                    acc[mi][ni] = __builtin_amdgcn_mfma_f32_16x16x32_bf16(aF[mi], bF[ni], acc[mi][ni], 0, 0, 0);
        }
        __syncthreads();
    }

    // epilogue: + b2, plain fp32 store (no atomics); padded rows are dead
    int q = l >> 4, cn = l & 15;
    float bias[4];
#pragma unroll
    for (int ni = 0; ni < 4; ++ni) bias[ni] = b2[e * DM + n0 + wn * 64 + ni * 16 + cn];
#pragma unroll
    for (int mi = 0; mi < 4; ++mi) {
#pragma unroll
        for (int rg = 0; rg < 4; ++rg) {
            int m = wm * 64 + mi * 16 + q * 4 + rg;
            float* orow = ypart + ((size_t)R0 + m) * DM;
#pragma unroll
            for (int ni = 0; ni < 4; ++ni)
                orow[n0 + wn * 64 + ni * 16 + cn] = acc[mi][ni][rg] + bias[ni];
        }
    }
}

// ---------------- gather: out[t] = g1*ypart[r1] + g2*ypart[r2] ----------------
__global__ __launch_bounds__(256) void k_gather(
    const float* __restrict__ yp, const int4* __restrict__ rec,
    const float2* __restrict__ gg, const int* __restrict__ offsets,
    float* __restrict__ out)
{
    int t = blockIdx.x;
    int4 rc = rec[t];
    float2 w = gg[t];
    size_t r1 = (size_t)offsets[rc.x] + rc.y;
    size_t r2 = (size_t)offsets[rc.z] + rc.w;
    const float4* a = (const float4*)(yp + r1 * DM);
    const float4* b = (const float4*)(yp + r2 * DM);
    float4 va = a[threadIdx.x], vb = b[threadIdx.x];
    float4 o;
    o.x = w.x * va.x + w.y * vb.x;
    o.y = w.x * va.y + w.y * vb.y;
    o.z = w.x * va.z + w.y * vb.z;
    o.w = w.x * va.w + w.y * vb.w;
    ((float4*)(out + (size_t)t * DM))[threadIdx.x] = o;
}

extern "C" void kernel_launch(void* const* d_in, const int* in_sizes, int n_in,
                              void* d_out, int out_size, void* d_ws, size_t ws_size,
                              hipStream_t stream)
{
    const float* x  = (const float*)d_in[0];
    const float* rw = (const float*)d_in[1];
    const float* rb = (const float*)d_in[2];
    const float* w1 = (const float*)d_in[3];
    const float* b1 = (const float*)d_in[4];
    const float* w2 = (const float*)d_in[5];
    const float* b2 = (const float*)d_in[6];
    float* out = (float*)d_out;

    char* ws = (char*)d_ws;
    // workspace layout — footprint 214,270,464 B (proven).
    // w2p ALIASES apack+w1p region: written by 2nd k_packw AFTER k_ffn1 consumed both.
    int*            counts   = (int*)(ws + 0);
    int*            offsets  = (int*)(ws + 128);
    int*            listTok  = (int*)(ws + 512);
    unsigned short* apack    = (unsigned short*)(ws + 262656);     // 21.0 MB [16][10240][64]
    unsigned short* w2p      = (unsigned short*)(ws + 262656);     // 64 MB (alias, after ffn1)
    unsigned short* w1p      = (unsigned short*)(ws + 21234176);   // 64 MB
    unsigned short* Hp       = (unsigned short*)(ws + 88343040);   // 83.9 MB [64][10240][64]
    float*          ypart    = (float*)(ws + 172229120);           // 41.9 MB [10240][1024]
    int4*           tokRec   = (int4*)(ws + 214172160);            // 64 KB
    float2*         tokGate  = (float2*)(ws + 214237696);          // 32 KB

    hipMemsetAsync(counts, 0, 32, stream);

    k_router <<<T_TOK / 4, 256, 0, stream>>>(x, rw, rb, counts, listTok, tokRec, tokGate);
    k_offsets<<<1, 1, 0, stream>>>(counts, offsets);
    k_packw  <<<dim3(DF / 64, DM / 64, NE), 256, 0, stream>>>(w1, w1p, DM, DF);
    k_packa  <<<dim3(PADROWS / 64, 16), 256, 0, stream>>>(x, listTok, counts, offsets, apack);
    k_ffn1   <<<NE * 32 * 32, 256, 0, stream>>>(apack, w1p, b1, counts, offsets, Hp);
    k_packw  <<<dim3(DM / 64, DF / 64, NE), 256, 0, stream>>>(w2, w2p, DF, DM);
    k_ffn2   <<<NE * 32 * 8, 256, 0, stream>>>(Hp, w2p, b2, counts, offsets, ypart);
    k_gather <<<T_TOK, 256, 0, stream>>>(ypart, tokRec, tokGate, offsets, out);
}